// Round 1
// baseline (1939.987 us; speedup 1.0000x reference)
//
#include <hip/hip_runtime.h>

#define N_NODES 100000
#define N_EDGES 1000000
#define N_GRAPHS 512
#define N_CLS 10
#define BN_EPS 1e-5f

// ---------------------------------------------------------------- utilities

__global__ void copy4_kernel(const float4* __restrict__ src, float4* __restrict__ dst, int n4) {
    int i = blockIdx.x * blockDim.x + threadIdx.x;
    if (i < n4) dst[i] = src[i];
}

__global__ void zero_kernel(float* __restrict__ p, int n) {
    int i = blockIdx.x * blockDim.x + threadIdx.x;
    if (i < n) p[i] = 0.f;
}

// ---------------------------------------------------------------- scatter-add
// 16 threads per edge, float4 per thread: gather feat[src] row, atomicAdd into agg[dst].
__global__ __launch_bounds__(256) void scatter_kernel(const float4* __restrict__ feat,
                                                      float* __restrict__ agg,
                                                      const int* __restrict__ srcI,
                                                      const int* __restrict__ dstI) {
    int t = blockIdx.x * 256 + threadIdx.x;
    int e = t >> 4;
    int q = t & 15;
    if (e >= N_EDGES) return;
    int s = srcI[e];
    int d = dstI[e];
    float4 v = feat[(size_t)s * 16 + q];
    float* ap = agg + (size_t)d * 64 + q * 4;
    atomicAdd(ap + 0, v.x);
    atomicAdd(ap + 1, v.y);
    atomicAdd(ap + 2, v.z);
    atomicAdd(ap + 3, v.w);
}

// ---------------------------------------------------------------- fused MLP
// One node per wave. Lane j owns output feature j. Weight columns live in VGPRs
// (wa_r/wb_r, 128 regs). Input row is read at a wave-uniform address (readfirstlane)
// so it lowers to scalar/broadcast loads. Second linear crosses lanes via v_readlane.
// BN folded into linear-1 scale/bias.
template <int RELU_OUT, int POOL>
__global__ __launch_bounds__(256)
void mlp_kernel(const float* __restrict__ in,
                const float* __restrict__ wa, const float* __restrict__ ba,
                const float* __restrict__ gg, const float* __restrict__ be,
                const float* __restrict__ mm, const float* __restrict__ vv,
                const float* __restrict__ wb, const float* __restrict__ bb,
                float* __restrict__ out0, float* __restrict__ out1,
                const int* __restrict__ batch, float* __restrict__ pooled) {
    const int j = threadIdx.x & 63;
    const int wv = threadIdx.x >> 6;
    const int gw = blockIdx.x * 4 + wv;
    const int nwaves = gridDim.x * 4;

    const float sbn = rsqrtf(vv[j] + BN_EPS) * gg[j];
    const float bias1 = (ba[j] - mm[j]) * sbn + be[j];
    const float bias2 = bb[j];

    float wa_r[64], wb_r[64];
#pragma unroll
    for (int k = 0; k < 64; ++k) {
        wa_r[k] = wa[k * 64 + j] * sbn;   // coalesced: lanes read consecutive j
        wb_r[k] = wb[k * 64 + j];
    }

    for (int n = gw; n < N_NODES; n += nwaves) {
        const int nu = __builtin_amdgcn_readfirstlane(n);
        const float4* __restrict__ row4 = (const float4*)(in + (size_t)nu * 64);

        // linear1 (+ folded BN)
        float t = bias1;
#pragma unroll
        for (int kq = 0; kq < 16; ++kq) {
            float4 r = row4[kq];          // wave-uniform address -> scalar/broadcast load
            t = fmaf(r.x, wa_r[4 * kq + 0], t);
            t = fmaf(r.y, wa_r[4 * kq + 1], t);
            t = fmaf(r.z, wa_r[4 * kq + 2], t);
            t = fmaf(r.w, wa_r[4 * kq + 3], t);
        }
        t = fmaxf(t, 0.f);                // ReLU after BN

        // linear2: t is lane-distributed; broadcast each t[k] via readlane
        float o = bias2;
#pragma unroll
        for (int k = 0; k < 64; ++k) {
            float s = __int_as_float(__builtin_amdgcn_readlane(__float_as_int(t), k));
            o = fmaf(s, wb_r[k], o);
        }

        if (POOL) {
            const int b = __builtin_amdgcn_readfirstlane(batch[nu]);
            atomicAdd(&pooled[b * 64 + j], o);
        } else {
            if (RELU_OUT) o = fmaxf(o, 0.f);
            out0[(size_t)nu * 64 + j] = o;
            if (out1) out1[(size_t)nu * 64 + j] = o;
        }
    }
}

// ---------------------------------------------------------------- classifier
__device__ __forceinline__ int lbound(const int* __restrict__ a, int n, int val) {
    int lo = 0, hi = n;
    while (lo < hi) {
        int mid = (lo + hi) >> 1;
        if (a[mid] < val) lo = mid + 1; else hi = mid;
    }
    return lo;
}

__global__ __launch_bounds__(64) void classifier_kernel(const float* __restrict__ pooled,
                                                        const int* __restrict__ batch,
                                                        const float* __restrict__ wc,
                                                        const float* __restrict__ bc,
                                                        float* __restrict__ out) {
    const int g = blockIdx.x;
    const int j = threadIdx.x;  // 64
    // node count for graph g via binary search over sorted batch (uniform across lanes)
    const int lo = lbound(batch, N_NODES, g);
    const int hi = lbound(batch, N_NODES, g + 1);
    const float c = fmaxf((float)(hi - lo), 1.f);
    const float mean = pooled[g * 64 + j] / c;
#pragma unroll
    for (int cc = 0; cc < N_CLS; ++cc) {
        float p = mean * wc[j * N_CLS + cc];
#pragma unroll
        for (int off = 32; off > 0; off >>= 1) p += __shfl_down(p, off, 64);
        if (j == 0) out[g * N_CLS + cc] = p + bc[cc];
    }
}

// ---------------------------------------------------------------- launch

extern "C" void kernel_launch(void* const* d_in, const int* in_sizes, int n_in,
                              void* d_out, int out_size, void* d_ws, size_t ws_size,
                              hipStream_t stream) {
    const float* x   = (const float*)d_in[0];
    const int*   ei  = (const int*)d_in[1];
    const int* batch = (const int*)d_in[2];
    const float* w0a = (const float*)d_in[3];
    const float* b0a = (const float*)d_in[4];
    const float* g0  = (const float*)d_in[5];
    const float* be0 = (const float*)d_in[6];
    const float* m0  = (const float*)d_in[7];
    const float* v0  = (const float*)d_in[8];
    const float* w0b = (const float*)d_in[9];
    const float* b0b = (const float*)d_in[10];
    const float* w1a = (const float*)d_in[11];
    const float* b1a = (const float*)d_in[12];
    const float* g1  = (const float*)d_in[13];
    const float* be1 = (const float*)d_in[14];
    const float* m1  = (const float*)d_in[15];
    const float* v1  = (const float*)d_in[16];
    const float* w1b = (const float*)d_in[17];
    const float* b1b = (const float*)d_in[18];
    const float* wc  = (const float*)d_in[19];
    const float* bc  = (const float*)d_in[20];
    float* out = (float*)d_out;

    float* bufA   = (float*)d_ws;                       // agg buffer, N*64 f32
    float* bufB   = bufA + (size_t)N_NODES * 64;        // h1 buffer,  N*64 f32
    float* pooled = bufB + (size_t)N_NODES * 64;        // 512*64 f32

    const int* srcI = ei;
    const int* dstI = ei + N_EDGES;

    // agg0 = x  (copy), pooled = 0
    copy4_kernel<<<(N_NODES * 16 + 255) / 256, 256, 0, stream>>>((const float4*)x, (float4*)bufA,
                                                                 N_NODES * 16);
    zero_kernel<<<(N_GRAPHS * 64 + 255) / 256, 256, 0, stream>>>(pooled, N_GRAPHS * 64);

    // agg0 += scatter(x[src] -> dst)
    scatter_kernel<<<(N_EDGES * 16) / 256, 256, 0, stream>>>((const float4*)x, bufA, srcI, dstI);

    // h1 = relu(mlp0(agg0)) -> bufB, and also seed agg1 (bufA) with h1
    mlp_kernel<1, 0><<<2048, 256, 0, stream>>>(bufA, w0a, b0a, g0, be0, m0, v0, w0b, b0b,
                                               bufB, bufA, nullptr, nullptr);

    // agg1 += scatter(h1[src] -> dst)
    scatter_kernel<<<(N_EDGES * 16) / 256, 256, 0, stream>>>((const float4*)bufB, bufA, srcI, dstI);

    // h2 = mlp1(agg1), fused mean-pool numerator via atomics
    mlp_kernel<0, 1><<<2048, 256, 0, stream>>>(bufA, w1a, b1a, g1, be1, m1, v1, w1b, b1b,
                                               nullptr, nullptr, batch, pooled);

    // out = (pooled / count) @ wc + bc
    classifier_kernel<<<N_GRAPHS, 64, 0, stream>>>(pooled, batch, wc, bc, out);
}

// Round 2
// 731.721 us; speedup vs baseline: 2.6513x; 2.6513x over previous
//
#include <hip/hip_runtime.h>

#define N_NODES 100000
#define N_EDGES 1000000
#define N_GRAPHS 512
#define N_CLS 10
#define BN_EPS 1e-5f

// ---------------------------------------------------------------- small utils

__global__ void zero_kernel(int* __restrict__ p, int n) {
    int i = blockIdx.x * blockDim.x + threadIdx.x;
    if (i < n) p[i] = 0;
}

// deg[dst]++ over all edges (int atomics: 1M ops, ~15us at measured atomic rate)
__global__ __launch_bounds__(256) void hist_kernel(const int* __restrict__ dstI,
                                                   int* __restrict__ deg) {
    int e = blockIdx.x * 256 + threadIdx.x;
    if (e < N_EDGES) atomicAdd(&deg[dstI[e]], 1);
}

// Single-workgroup exclusive scan of deg -> rowptr, cursor (1024 threads, chunked).
#define SCAN_T 1024
#define SCAN_CHUNK 98  // 1024*98 = 100352 >= 100000
__global__ __launch_bounds__(SCAN_T) void scan_kernel(const int* __restrict__ deg,
                                                      int* __restrict__ rowptr,
                                                      int* __restrict__ cursor) {
    __shared__ int sh[SCAN_T];
    const int tid = threadIdx.x;
    const int base = tid * SCAN_CHUNK;
    int sum = 0;
    for (int i = 0; i < SCAN_CHUNK; ++i) {
        int idx = base + i;
        if (idx < N_NODES) sum += deg[idx];
    }
    sh[tid] = sum;
    __syncthreads();
    for (int off = 1; off < SCAN_T; off <<= 1) {
        int v = (tid >= off) ? sh[tid - off] : 0;
        __syncthreads();
        sh[tid] += v;
        __syncthreads();
    }
    int run = sh[tid] - sum;  // exclusive prefix of this chunk
    for (int i = 0; i < SCAN_CHUNK; ++i) {
        int idx = base + i;
        if (idx < N_NODES) {
            rowptr[idx] = run;
            cursor[idx] = run;
            run += deg[idx];
        }
    }
    if (tid == SCAN_T - 1) rowptr[N_NODES] = sh[SCAN_T - 1];  // total = 1M
}

// sortedSrc[cursor[dst]++] = src  (1M int atomics + 1M scattered 4B writes)
__global__ __launch_bounds__(256) void fill_kernel(const int* __restrict__ srcI,
                                                   const int* __restrict__ dstI,
                                                   int* __restrict__ cursor,
                                                   int* __restrict__ sortedSrc) {
    int e = blockIdx.x * 256 + threadIdx.x;
    if (e >= N_EDGES) return;
    int p = atomicAdd(&cursor[dstI[e]], 1);
    sortedSrc[p] = srcI[e];
}

// ---------------------------------------------------------------- fused conv
// One node per wave, lane j owns feature column j.
//   agg[j] = in[n][j] + sum_{e in CSR[n]} in[src[e]][j]   (coalesced gathers)
//   h = relu(BN(agg @ wa + ba)) ; o = h @ wb + bb          (cross-lane via readlane)
// Weight columns stay in VGPRs (128 regs), loaded once per wave (grid-stride).
template <int RELU_OUT, int POOL>
__global__ __launch_bounds__(256)
void conv_kernel(const float* __restrict__ in,
                 const int* __restrict__ rowptr, const int* __restrict__ srcList,
                 const float* __restrict__ wa, const float* __restrict__ ba,
                 const float* __restrict__ gg, const float* __restrict__ be,
                 const float* __restrict__ mm, const float* __restrict__ vv,
                 const float* __restrict__ wb, const float* __restrict__ bb,
                 float* __restrict__ out,
                 const int* __restrict__ batch, float* __restrict__ pooled) {
    const int j = threadIdx.x & 63;
    const int wv = threadIdx.x >> 6;
    const int gw = blockIdx.x * 4 + wv;
    const int nwaves = gridDim.x * 4;

    const float sbn = rsqrtf(vv[j] + BN_EPS) * gg[j];
    const float bias1 = (ba[j] - mm[j]) * sbn + be[j];
    const float bias2 = bb[j];

    float wa_r[64], wb_r[64];
#pragma unroll
    for (int k = 0; k < 64; ++k) {
        wa_r[k] = wa[k * 64 + j] * sbn;   // coalesced over j
        wb_r[k] = wb[k * 64 + j];
    }

    for (int n = gw; n < N_NODES; n += nwaves) {
        const int nu = __builtin_amdgcn_readfirstlane(n);
        const int r0 = __builtin_amdgcn_readfirstlane(rowptr[nu]);
        const int r1 = __builtin_amdgcn_readfirstlane(rowptr[nu + 1]);

        // gather-aggregate: self + neighbors, 4 accumulators to break load latency chain
        float t0 = in[nu * 64 + j], t1 = 0.f, t2 = 0.f, t3 = 0.f;
        for (int eb = r0; eb < r1; eb += 64) {
            const int cnt = min(64, r1 - eb);
            const int vsrc = (eb + j < r1) ? srcList[eb + j] : 0;  // coalesced
            int i = 0;
            for (; i + 4 <= cnt; i += 4) {
                int s0 = __builtin_amdgcn_readlane(vsrc, i + 0);
                int s1 = __builtin_amdgcn_readlane(vsrc, i + 1);
                int s2 = __builtin_amdgcn_readlane(vsrc, i + 2);
                int s3 = __builtin_amdgcn_readlane(vsrc, i + 3);
                t0 += in[s0 * 64 + j];
                t1 += in[s1 * 64 + j];
                t2 += in[s2 * 64 + j];
                t3 += in[s3 * 64 + j];
            }
            for (; i < cnt; ++i) {
                int s = __builtin_amdgcn_readlane(vsrc, i);
                t0 += in[s * 64 + j];
            }
        }
        const float t = (t0 + t1) + (t2 + t3);  // lane j holds agg[j]

        // linear1 (+folded BN) -> ReLU : lane j needs all agg[k], broadcast via readlane
        float h = bias1;
#pragma unroll
        for (int k = 0; k < 64; ++k) {
            float s = __int_as_float(__builtin_amdgcn_readlane(__float_as_int(t), k));
            h = fmaf(s, wa_r[k], h);
        }
        h = fmaxf(h, 0.f);

        // linear2
        float o = bias2;
#pragma unroll
        for (int k = 0; k < 64; ++k) {
            float s = __int_as_float(__builtin_amdgcn_readlane(__float_as_int(h), k));
            o = fmaf(s, wb_r[k], o);
        }

        if (POOL) {
            const int b = __builtin_amdgcn_readfirstlane(batch[nu]);
            atomicAdd(&pooled[b * 64 + j], o);
        } else {
            if (RELU_OUT) o = fmaxf(o, 0.f);
            out[nu * 64 + j] = o;
        }
    }
}

// ---------------------------------------------------------------- classifier
__device__ __forceinline__ int lbound(const int* __restrict__ a, int n, int val) {
    int lo = 0, hi = n;
    while (lo < hi) {
        int mid = (lo + hi) >> 1;
        if (a[mid] < val) lo = mid + 1; else hi = mid;
    }
    return lo;
}

__global__ __launch_bounds__(64) void classifier_kernel(const float* __restrict__ pooled,
                                                        const int* __restrict__ batch,
                                                        const float* __restrict__ wc,
                                                        const float* __restrict__ bc,
                                                        float* __restrict__ out) {
    const int g = blockIdx.x;
    const int j = threadIdx.x;  // 64
    const int lo = lbound(batch, N_NODES, g);
    const int hi = lbound(batch, N_NODES, g + 1);
    const float c = fmaxf((float)(hi - lo), 1.f);
    const float mean = pooled[g * 64 + j] / c;
#pragma unroll
    for (int cc = 0; cc < N_CLS; ++cc) {
        float p = mean * wc[j * N_CLS + cc];
#pragma unroll
        for (int off = 32; off > 0; off >>= 1) p += __shfl_down(p, off, 64);
        if (j == 0) out[g * N_CLS + cc] = p + bc[cc];
    }
}

// ---------------------------------------------------------------- launch

extern "C" void kernel_launch(void* const* d_in, const int* in_sizes, int n_in,
                              void* d_out, int out_size, void* d_ws, size_t ws_size,
                              hipStream_t stream) {
    const float* x   = (const float*)d_in[0];
    const int*   ei  = (const int*)d_in[1];
    const int* batch = (const int*)d_in[2];
    const float* w0a = (const float*)d_in[3];
    const float* b0a = (const float*)d_in[4];
    const float* g0  = (const float*)d_in[5];
    const float* be0 = (const float*)d_in[6];
    const float* m0  = (const float*)d_in[7];
    const float* v0  = (const float*)d_in[8];
    const float* w0b = (const float*)d_in[9];
    const float* b0b = (const float*)d_in[10];
    const float* w1a = (const float*)d_in[11];
    const float* b1a = (const float*)d_in[12];
    const float* g1  = (const float*)d_in[13];
    const float* be1 = (const float*)d_in[14];
    const float* m1  = (const float*)d_in[15];
    const float* v1  = (const float*)d_in[16];
    const float* w1b = (const float*)d_in[17];
    const float* b1b = (const float*)d_in[18];
    const float* wc  = (const float*)d_in[19];
    const float* bc  = (const float*)d_in[20];
    float* out = (float*)d_out;

    const int* srcI = ei;
    const int* dstI = ei + N_EDGES;

    // workspace layout (all 4B elems): deg | pooled | rowptr | cursor | sortedSrc | h1
    int*   deg       = (int*)d_ws;                       // 100000
    float* pooled    = (float*)(deg + N_NODES);          // 32768
    int*   rowptr    = (int*)(pooled + N_GRAPHS * 64);   // 100001
    int*   cursor    = rowptr + N_NODES + 1;             // 100000
    int*   sortedSrc = cursor + N_NODES;                 // 1000000
    float* h1        = (float*)(sortedSrc + N_EDGES);    // 6400000
    // total ~30.9 MB

    // zero deg + pooled (contiguous region)
    const int nz = N_NODES + N_GRAPHS * 64;
    zero_kernel<<<(nz + 255) / 256, 256, 0, stream>>>(deg, nz);

    // build CSR (by dst) once; reused by both convs
    hist_kernel<<<(N_EDGES + 255) / 256, 256, 0, stream>>>(dstI, deg);
    scan_kernel<<<1, SCAN_T, 0, stream>>>(deg, rowptr, cursor);
    fill_kernel<<<(N_EDGES + 255) / 256, 256, 0, stream>>>(srcI, dstI, cursor, sortedSrc);

    // conv0: h1 = relu(mlp0(x + gather(x)))
    conv_kernel<1, 0><<<2048, 256, 0, stream>>>(x, rowptr, sortedSrc,
                                                w0a, b0a, g0, be0, m0, v0, w0b, b0b,
                                                h1, nullptr, nullptr);

    // conv1: pooled += mlp1(h1 + gather(h1)) per graph
    conv_kernel<0, 1><<<2048, 256, 0, stream>>>(h1, rowptr, sortedSrc,
                                                w1a, b1a, g1, be1, m1, v1, w1b, b1b,
                                                nullptr, batch, pooled);

    // out = (pooled / count) @ wc + bc
    classifier_kernel<<<N_GRAPHS, 64, 0, stream>>>(pooled, batch, wc, bc, out);
}

// Round 3
// 482.464 us; speedup vs baseline: 4.0210x; 1.5166x over previous
//
#include <hip/hip_runtime.h>

#define N_NODES 100000
#define N_EDGES 1000000
#define N_GRAPHS 512
#define N_CLS 10
#define BN_EPS 1e-5f

#define SCAN_NB 200   // 200 * 512 = 102400 >= N_NODES

// ---------------------------------------------------------------- small utils

__global__ void zero_kernel(int* __restrict__ p, int n) {
    int i = blockIdx.x * blockDim.x + threadIdx.x;
    if (i < n) p[i] = 0;
}

// deg[dst]++ over all edges
__global__ __launch_bounds__(256) void hist_kernel(const int* __restrict__ dstI,
                                                   int* __restrict__ deg) {
    int e = blockIdx.x * 256 + threadIdx.x;
    if (e < N_EDGES) atomicAdd(&deg[dstI[e]], 1);
}

// ---- decoupled 3-phase exclusive scan of deg -> rowptr/cursor ----
__global__ __launch_bounds__(256) void scanA_kernel(const int* __restrict__ deg,
                                                    int* __restrict__ bsum) {
    __shared__ int sh[256];
    const int base = blockIdx.x * 512;
    const int t = threadIdx.x;
    int a = 0, b = 0;
    if (base + t < N_NODES) a = deg[base + t];
    if (base + 256 + t < N_NODES) b = deg[base + 256 + t];
    sh[t] = a + b;
    __syncthreads();
#pragma unroll
    for (int off = 128; off > 0; off >>= 1) {
        if (t < off) sh[t] += sh[t + off];
        __syncthreads();
    }
    if (t == 0) bsum[blockIdx.x] = sh[0];
}

__global__ __launch_bounds__(256) void scanB_kernel(const int* __restrict__ bsum,
                                                    int* __restrict__ boff,
                                                    int* __restrict__ rowptr) {
    __shared__ int sh[256];
    const int t = threadIdx.x;
    const int v = (t < SCAN_NB) ? bsum[t] : 0;
    sh[t] = v;
    __syncthreads();
#pragma unroll
    for (int off = 1; off < 256; off <<= 1) {
        int u = (t >= off) ? sh[t - off] : 0;
        __syncthreads();
        sh[t] += u;
        __syncthreads();
    }
    if (t < SCAN_NB) boff[t] = sh[t] - v;          // exclusive block offset
    if (t == 0) rowptr[N_NODES] = N_EDGES;         // total is a known constant
}

__global__ __launch_bounds__(256) void scanC_kernel(const int* __restrict__ deg,
                                                    const int* __restrict__ boff,
                                                    int* __restrict__ rowptr,
                                                    int* __restrict__ cursor) {
    __shared__ int sh[256];
    const int base = blockIdx.x * 512;
    const int t = threadIdx.x;
    const int i0 = base + 2 * t, i1 = i0 + 1;
    const int d0 = (i0 < N_NODES) ? deg[i0] : 0;
    const int d1 = (i1 < N_NODES) ? deg[i1] : 0;
    const int p = d0 + d1;
    sh[t] = p;
    __syncthreads();
#pragma unroll
    for (int off = 1; off < 256; off <<= 1) {
        int u = (t >= off) ? sh[t - off] : 0;
        __syncthreads();
        sh[t] += u;
        __syncthreads();
    }
    const int excl = boff[blockIdx.x] + sh[t] - p;
    if (i0 < N_NODES) { rowptr[i0] = excl;      cursor[i0] = excl; }
    if (i1 < N_NODES) { rowptr[i1] = excl + d0; cursor[i1] = excl + d0; }
}

// sortedSrc[cursor[dst]++] = src
__global__ __launch_bounds__(256) void fill_kernel(const int* __restrict__ srcI,
                                                   const int* __restrict__ dstI,
                                                   int* __restrict__ cursor,
                                                   int* __restrict__ sortedSrc) {
    int e = blockIdx.x * 256 + threadIdx.x;
    if (e >= N_EDGES) return;
    int p = atomicAdd(&cursor[dstI[e]], 1);
    sortedSrc[p] = srcI[e];
}

// graph boundaries from sorted batch: gstart[g] = first node index with batch >= g
__global__ __launch_bounds__(256) void bounds_kernel(const int* __restrict__ batch,
                                                     int* __restrict__ gstart) {
    int i = blockIdx.x * 256 + threadIdx.x;
    if (i > N_NODES) return;
    int bcur = (i < N_NODES) ? batch[i] : N_GRAPHS;
    int bprev = (i > 0) ? batch[i - 1] : -1;
    for (int g = bprev + 1; g <= bcur; ++g) gstart[g] = i;
}

// ---------------------------------------------------------------- fused conv
// One node per wave, lane j owns feature column j.
template <int RELU_OUT, int POOL>
__global__ __launch_bounds__(256)
void conv_kernel(const float* __restrict__ in,
                 const int* __restrict__ rowptr, const int* __restrict__ srcList,
                 const float* __restrict__ wa, const float* __restrict__ ba,
                 const float* __restrict__ gg, const float* __restrict__ be,
                 const float* __restrict__ mm, const float* __restrict__ vv,
                 const float* __restrict__ wb, const float* __restrict__ bb,
                 float* __restrict__ out,
                 const int* __restrict__ batch, float* __restrict__ pooled) {
    const int j = threadIdx.x & 63;
    const int wv = threadIdx.x >> 6;
    const int gw = blockIdx.x * 4 + wv;
    const int nwaves = gridDim.x * 4;

    const float sbn = rsqrtf(vv[j] + BN_EPS) * gg[j];
    const float bias1 = (ba[j] - mm[j]) * sbn + be[j];
    const float bias2 = bb[j];

    float wa_r[64], wb_r[64];
#pragma unroll
    for (int k = 0; k < 64; ++k) {
        wa_r[k] = wa[k * 64 + j] * sbn;
        wb_r[k] = wb[k * 64 + j];
    }

    for (int n = gw; n < N_NODES; n += nwaves) {
        const int nu = __builtin_amdgcn_readfirstlane(n);
        const int r0 = __builtin_amdgcn_readfirstlane(rowptr[nu]);
        const int r1 = __builtin_amdgcn_readfirstlane(rowptr[nu + 1]);

        float t0 = in[nu * 64 + j], t1 = 0.f, t2 = 0.f, t3 = 0.f;
        for (int eb = r0; eb < r1; eb += 64) {
            const int cnt = min(64, r1 - eb);
            const int vsrc = (eb + j < r1) ? srcList[eb + j] : 0;
            int i = 0;
            for (; i + 4 <= cnt; i += 4) {
                int s0 = __builtin_amdgcn_readlane(vsrc, i + 0);
                int s1 = __builtin_amdgcn_readlane(vsrc, i + 1);
                int s2 = __builtin_amdgcn_readlane(vsrc, i + 2);
                int s3 = __builtin_amdgcn_readlane(vsrc, i + 3);
                t0 += in[s0 * 64 + j];
                t1 += in[s1 * 64 + j];
                t2 += in[s2 * 64 + j];
                t3 += in[s3 * 64 + j];
            }
            for (; i < cnt; ++i) {
                int s = __builtin_amdgcn_readlane(vsrc, i);
                t0 += in[s * 64 + j];
            }
        }
        const float t = (t0 + t1) + (t2 + t3);

        float h = bias1;
#pragma unroll
        for (int k = 0; k < 64; ++k) {
            float s = __int_as_float(__builtin_amdgcn_readlane(__float_as_int(t), k));
            h = fmaf(s, wa_r[k], h);
        }
        h = fmaxf(h, 0.f);

        float o = bias2;
#pragma unroll
        for (int k = 0; k < 64; ++k) {
            float s = __int_as_float(__builtin_amdgcn_readlane(__float_as_int(h), k));
            o = fmaf(s, wb_r[k], o);
        }

        if (POOL) {
            const int b = __builtin_amdgcn_readfirstlane(batch[nu]);
            atomicAdd(&pooled[b * 64 + j], o);
        } else {
            if (RELU_OUT) o = fmaxf(o, 0.f);
            out[nu * 64 + j] = o;
        }
    }
}

// ---------------------------------------------------------------- classifier
__global__ __launch_bounds__(64) void classifier_kernel(const float* __restrict__ pooled,
                                                        const int* __restrict__ gstart,
                                                        const float* __restrict__ wc,
                                                        const float* __restrict__ bc,
                                                        float* __restrict__ out) {
    const int g = blockIdx.x;
    const int j = threadIdx.x;  // 64
    const float c = fmaxf((float)(gstart[g + 1] - gstart[g]), 1.f);
    const float mean = pooled[g * 64 + j] / c;
#pragma unroll
    for (int cc = 0; cc < N_CLS; ++cc) {
        float p = mean * wc[j * N_CLS + cc];
#pragma unroll
        for (int off = 32; off > 0; off >>= 1) p += __shfl_down(p, off, 64);
        if (j == 0) out[g * N_CLS + cc] = p + bc[cc];
    }
}

// ---------------------------------------------------------------- launch

extern "C" void kernel_launch(void* const* d_in, const int* in_sizes, int n_in,
                              void* d_out, int out_size, void* d_ws, size_t ws_size,
                              hipStream_t stream) {
    const float* x   = (const float*)d_in[0];
    const int*   ei  = (const int*)d_in[1];
    const int* batch = (const int*)d_in[2];
    const float* w0a = (const float*)d_in[3];
    const float* b0a = (const float*)d_in[4];
    const float* g0  = (const float*)d_in[5];
    const float* be0 = (const float*)d_in[6];
    const float* m0  = (const float*)d_in[7];
    const float* v0  = (const float*)d_in[8];
    const float* w0b = (const float*)d_in[9];
    const float* b0b = (const float*)d_in[10];
    const float* w1a = (const float*)d_in[11];
    const float* b1a = (const float*)d_in[12];
    const float* g1  = (const float*)d_in[13];
    const float* be1 = (const float*)d_in[14];
    const float* m1  = (const float*)d_in[15];
    const float* v1  = (const float*)d_in[16];
    const float* w1b = (const float*)d_in[17];
    const float* b1b = (const float*)d_in[18];
    const float* wc  = (const float*)d_in[19];
    const float* bc  = (const float*)d_in[20];
    float* out = (float*)d_out;

    const int* srcI = ei;
    const int* dstI = ei + N_EDGES;

    // workspace layout (4B elems)
    int*   deg       = (int*)d_ws;                       // 100000
    float* pooled    = (float*)(deg + N_NODES);          // 32768
    int*   rowptr    = (int*)(pooled + N_GRAPHS * 64);   // 100001
    int*   cursor    = rowptr + N_NODES + 1;             // 100000
    int*   sortedSrc = cursor + N_NODES;                 // 1000000
    float* h1        = (float*)(sortedSrc + N_EDGES);    // 6400000
    int*   bsum      = (int*)(h1 + (size_t)N_NODES * 64);// 200
    int*   boff      = bsum + SCAN_NB;                   // 200
    int*   gstart    = boff + SCAN_NB;                   // 513

    // zero deg + pooled (contiguous)
    const int nz = N_NODES + N_GRAPHS * 64;
    zero_kernel<<<(nz + 255) / 256, 256, 0, stream>>>(deg, nz);

    // build CSR (by dst): hist -> 3-phase scan -> fill
    hist_kernel<<<(N_EDGES + 255) / 256, 256, 0, stream>>>(dstI, deg);
    scanA_kernel<<<SCAN_NB, 256, 0, stream>>>(deg, bsum);
    scanB_kernel<<<1, 256, 0, stream>>>(bsum, boff, rowptr);
    scanC_kernel<<<SCAN_NB, 256, 0, stream>>>(deg, boff, rowptr, cursor);
    fill_kernel<<<(N_EDGES + 255) / 256, 256, 0, stream>>>(srcI, dstI, cursor, sortedSrc);

    // graph boundaries for mean-pool counts
    bounds_kernel<<<(N_NODES + 256) / 256, 256, 0, stream>>>(batch, gstart);

    // conv0: h1 = relu(mlp0(x + gather(x)))
    conv_kernel<1, 0><<<2048, 256, 0, stream>>>(x, rowptr, sortedSrc,
                                                w0a, b0a, g0, be0, m0, v0, w0b, b0b,
                                                h1, nullptr, nullptr);

    // conv1: pooled += mlp1(h1 + gather(h1))
    conv_kernel<0, 1><<<2048, 256, 0, stream>>>(h1, rowptr, sortedSrc,
                                                w1a, b1a, g1, be1, m1, v1, w1b, b1b,
                                                nullptr, batch, pooled);

    // out = (pooled / count) @ wc + bc
    classifier_kernel<<<N_GRAPHS, 64, 0, stream>>>(pooled, gstart, wc, bc, out);
}

// Round 4
// 411.798 us; speedup vs baseline: 4.7110x; 1.1716x over previous
//
#include <hip/hip_runtime.h>

#define N_NODES 100000
#define N_EDGES 1000000
#define N_GRAPHS 512
#define N_CLS 10
#define BN_EPS 1e-5f

#define SCAN_NB 200   // 200 * 512 = 102400 >= N_NODES
#define NTILES 1563   // ceil(100000/64)

typedef short short8 __attribute__((ext_vector_type(8)));
typedef float floatx4 __attribute__((ext_vector_type(4)));

__device__ __forceinline__ short f2bf(float f) {
    unsigned u = __float_as_uint(f);
    unsigned r = (u + 0x7FFFu + ((u >> 16) & 1u)) >> 16;
    return (short)r;
}
__device__ __forceinline__ float bf2f(short h) {
    return __uint_as_float(((unsigned)(unsigned short)h) << 16);
}

// ---------------------------------------------------------------- prep
// Fused: zero deg+pooled | graph bounds | pack W into bf16 hi/lo MFMA B-frags | fold BN biases
__global__ __launch_bounds__(256) void prep_kernel(
    const int* __restrict__ batch,
    const float* __restrict__ w0a, const float* __restrict__ b0a,
    const float* __restrict__ g0, const float* __restrict__ be0,
    const float* __restrict__ m0, const float* __restrict__ v0,
    const float* __restrict__ w0b,
    const float* __restrict__ w1a, const float* __restrict__ b1a,
    const float* __restrict__ g1, const float* __restrict__ be1,
    const float* __restrict__ m1, const float* __restrict__ v1,
    const float* __restrict__ w1b,
    int* __restrict__ zeroBase, int nz,
    int* __restrict__ gstart,
    short* __restrict__ wHi, short* __restrict__ wLo,
    float* __restrict__ b1p0, float* __restrict__ b1p1) {
    const int gid = blockIdx.x * 256 + threadIdx.x;

    if (gid < nz) zeroBase[gid] = 0;

    if (gid <= N_NODES) {  // graph boundaries from sorted batch
        int bcur = (gid < N_NODES) ? batch[gid] : N_GRAPHS;
        int bprev = (gid > 0) ? batch[gid - 1] : -1;
        for (int g = bprev + 1; g <= bcur; ++g) gstart[g] = gid;
    }

    if (gid < 16384) {  // W frag pack: [mat(4)][k0(2)][c(4)][lane(64)][jj(8)]
        const int e = gid & 4095, mat = gid >> 12;
        const int jj = e & 7, lane = (e >> 3) & 63, c = (e >> 9) & 3, k0 = (e >> 11) & 1;
        const int k = k0 * 32 + (lane >> 4) * 8 + jj;
        const int col = c * 16 + (lane & 15);
        float val;
        if (mat == 0)      val = w0a[k * 64 + col] * (rsqrtf(v0[col] + BN_EPS) * g0[col]);
        else if (mat == 1) val = w0b[k * 64 + col];
        else if (mat == 2) val = w1a[k * 64 + col] * (rsqrtf(v1[col] + BN_EPS) * g1[col]);
        else               val = w1b[k * 64 + col];
        short hi = f2bf(val);
        wHi[gid] = hi;
        wLo[gid] = f2bf(val - bf2f(hi));
    }

    if (gid >= 16384 && gid < 16512) {  // BN-folded biases
        int t = gid - 16384;
        if (t < 64) {
            float s = rsqrtf(v0[t] + BN_EPS) * g0[t];
            b1p0[t] = (b0a[t] - m0[t]) * s + be0[t];
        } else {
            t -= 64;
            float s = rsqrtf(v1[t] + BN_EPS) * g1[t];
            b1p1[t] = (b1a[t] - m1[t]) * s + be1[t];
        }
    }
}

// ---------------------------------------------------------------- CSR build
__global__ __launch_bounds__(256) void hist_kernel(const int* __restrict__ dstI,
                                                   int* __restrict__ deg) {
    int e = blockIdx.x * 256 + threadIdx.x;
    if (e < N_EDGES) atomicAdd(&deg[dstI[e]], 1);
}

__global__ __launch_bounds__(256) void scanA_kernel(const int* __restrict__ deg,
                                                    int* __restrict__ bsum) {
    __shared__ int sh[256];
    const int base = blockIdx.x * 512;
    const int t = threadIdx.x;
    int a = 0, b = 0;
    if (base + t < N_NODES) a = deg[base + t];
    if (base + 256 + t < N_NODES) b = deg[base + 256 + t];
    sh[t] = a + b;
    __syncthreads();
#pragma unroll
    for (int off = 128; off > 0; off >>= 1) {
        if (t < off) sh[t] += sh[t + off];
        __syncthreads();
    }
    if (t == 0) bsum[blockIdx.x] = sh[0];
}

__global__ __launch_bounds__(256) void scanB_kernel(const int* __restrict__ bsum,
                                                    int* __restrict__ boff,
                                                    int* __restrict__ rowptr) {
    __shared__ int sh[256];
    const int t = threadIdx.x;
    const int v = (t < SCAN_NB) ? bsum[t] : 0;
    sh[t] = v;
    __syncthreads();
#pragma unroll
    for (int off = 1; off < 256; off <<= 1) {
        int u = (t >= off) ? sh[t - off] : 0;
        __syncthreads();
        sh[t] += u;
        __syncthreads();
    }
    if (t < SCAN_NB) boff[t] = sh[t] - v;
    if (t == 0) rowptr[N_NODES] = N_EDGES;
}

__global__ __launch_bounds__(256) void scanC_kernel(const int* __restrict__ deg,
                                                    const int* __restrict__ boff,
                                                    int* __restrict__ rowptr,
                                                    int* __restrict__ cursor) {
    __shared__ int sh[256];
    const int base = blockIdx.x * 512;
    const int t = threadIdx.x;
    const int i0 = base + 2 * t, i1 = i0 + 1;
    const int d0 = (i0 < N_NODES) ? deg[i0] : 0;
    const int d1 = (i1 < N_NODES) ? deg[i1] : 0;
    const int p = d0 + d1;
    sh[t] = p;
    __syncthreads();
#pragma unroll
    for (int off = 1; off < 256; off <<= 1) {
        int u = (t >= off) ? sh[t - off] : 0;
        __syncthreads();
        sh[t] += u;
        __syncthreads();
    }
    const int excl = boff[blockIdx.x] + sh[t] - p;
    if (i0 < N_NODES) { rowptr[i0] = excl;      cursor[i0] = excl; }
    if (i1 < N_NODES) { rowptr[i1] = excl + d0; cursor[i1] = excl + d0; }
}

__global__ __launch_bounds__(256) void fill_kernel(const int* __restrict__ srcI,
                                                   const int* __restrict__ dstI,
                                                   int* __restrict__ cursor,
                                                   int* __restrict__ sortedSrc) {
    int e = blockIdx.x * 256 + threadIdx.x;
    if (e >= N_EDGES) return;
    int p = atomicAdd(&cursor[dstI[e]], 1);
    sortedSrc[p] = srcI[e];
}

// ---------------------------------------------------------------- fused conv (MFMA)
// Block = 256 thr = 4 waves, 64-node tile. Gather agg into LDS (bf16 hi/lo),
// then split-bf16 MFMA MLP: D = Ah@Wh + Al@Wh + Ah@Wl per linear.
// 16x16x32 bf16 layouts: A[m=lane&15][k=(lane>>4)*8+jj]; B[k=(lane>>4)*8+jj][n=lane&15];
// C/D: col=lane&15, row=(lane>>4)*4+reg.
template <int POOL>
__global__ __launch_bounds__(256) void conv_mfma(
    const float* __restrict__ in, const int* __restrict__ rowptr,
    const int* __restrict__ srcList,
    const short* __restrict__ wH1, const short* __restrict__ wL1,
    const short* __restrict__ wH2, const short* __restrict__ wL2,
    const float* __restrict__ b1, const float* __restrict__ b2,
    float* __restrict__ out, const int* __restrict__ batch,
    float* __restrict__ pooled) {
    __shared__ __align__(16) union SM {
        struct { short aggH[64 * 72]; short aggL[64 * 72]; } a;  // 18432 B
        float oT[64 * 66];                                       // 16896 B (reused post-MFMA)
    } U;
    __shared__ __align__(16) short hBuf[4][2 * 1152];  // per-wave H strip hi|lo
    __shared__ float pooledLoc[8 * 64];
    __shared__ int bIds[64];
    __shared__ int maxSlot;

    const int tid = threadIdx.x;
    const int j = tid & 63, wv = tid >> 6;
    const int base = blockIdx.x * 64;

    if (POOL) {
        pooledLoc[tid] = 0.f;
        pooledLoc[tid + 256] = 0.f;
        if (tid == 0) maxSlot = 0;
    }

    // ---- gather-aggregate into LDS (lane j owns feature j) ----
    for (int m = 0; m < 16; ++m) {
        const int ml = wv * 16 + m;
        const int node = base + ml;
        float t0 = 0.f, t1 = 0.f, t2 = 0.f, t3 = 0.f, t4 = 0.f, t5 = 0.f, t6 = 0.f, t7 = 0.f;
        if (node < N_NODES) {
            const int nu = __builtin_amdgcn_readfirstlane(node);
            t0 = in[nu * 64 + j];  // self (GIN eps=0)
            const int r0 = __builtin_amdgcn_readfirstlane(rowptr[nu]);
            const int r1 = __builtin_amdgcn_readfirstlane(rowptr[nu + 1]);
            for (int eb = r0; eb < r1; eb += 64) {
                const int cnt = min(64, r1 - eb);
                const int vsrc = (eb + j < r1) ? srcList[eb + j] : 0;
                int i = 0;
                for (; i + 8 <= cnt; i += 8) {
                    int s0 = __builtin_amdgcn_readlane(vsrc, i + 0);
                    int s1 = __builtin_amdgcn_readlane(vsrc, i + 1);
                    int s2 = __builtin_amdgcn_readlane(vsrc, i + 2);
                    int s3 = __builtin_amdgcn_readlane(vsrc, i + 3);
                    int s4 = __builtin_amdgcn_readlane(vsrc, i + 4);
                    int s5 = __builtin_amdgcn_readlane(vsrc, i + 5);
                    int s6 = __builtin_amdgcn_readlane(vsrc, i + 6);
                    int s7 = __builtin_amdgcn_readlane(vsrc, i + 7);
                    t0 += in[s0 * 64 + j]; t1 += in[s1 * 64 + j];
                    t2 += in[s2 * 64 + j]; t3 += in[s3 * 64 + j];
                    t4 += in[s4 * 64 + j]; t5 += in[s5 * 64 + j];
                    t6 += in[s6 * 64 + j]; t7 += in[s7 * 64 + j];
                }
                for (; i < cnt; ++i) {
                    int s = __builtin_amdgcn_readlane(vsrc, i);
                    t0 += in[s * 64 + j];
                }
            }
            if (POOL && j == 0) bIds[ml] = batch[nu];
        } else {
            if (POOL && j == 0) bIds[ml] = -1;
        }
        const float t = ((t0 + t1) + (t2 + t3)) + ((t4 + t5) + (t6 + t7));
        const short hi = f2bf(t);
        U.a.aggH[ml * 72 + j] = hi;
        U.a.aggL[ml * 72 + j] = f2bf(t - bf2f(hi));
    }

    const int l15 = j & 15, quad = j >> 4;
    const floatx4 vzero = {0.f, 0.f, 0.f, 0.f};

    // ---- linear1 (+BN fold) ----
    floatx4 acc[4] = {vzero, vzero, vzero, vzero};
    {
        const short* aH0 = U.a.aggH + (wv * 16 + l15) * 72 + quad * 8;
        const short* aL0 = U.a.aggL + (wv * 16 + l15) * 72 + quad * 8;
#pragma unroll
        for (int k0 = 0; k0 < 2; ++k0) {
            short8 aH = *(const short8*)(aH0 + k0 * 32);
            short8 aL = *(const short8*)(aL0 + k0 * 32);
#pragma unroll
            for (int c = 0; c < 4; ++c) {
                const int fo = ((k0 * 4 + c) * 64 + j) * 8;
                short8 bH = *(const short8*)(wH1 + fo);
                short8 bL = *(const short8*)(wL1 + fo);
                acc[c] = __builtin_amdgcn_mfma_f32_16x16x32_bf16(aH, bH, acc[c], 0, 0, 0);
                acc[c] = __builtin_amdgcn_mfma_f32_16x16x32_bf16(aL, bH, acc[c], 0, 0, 0);
                acc[c] = __builtin_amdgcn_mfma_f32_16x16x32_bf16(aH, bL, acc[c], 0, 0, 0);
            }
        }
    }
    // bias + relu + split into per-wave H strip
    short* hH = hBuf[wv];
    short* hL = hH + 1152;
#pragma unroll
    for (int c = 0; c < 4; ++c) {
        const float bv = b1[c * 16 + l15];
#pragma unroll
        for (int r = 0; r < 4; ++r) {
            const int row = quad * 4 + r, col = c * 16 + l15;
            float v = acc[c][r] + bv;
            v = fmaxf(v, 0.f);
            const short hi = f2bf(v);
            hH[row * 72 + col] = hi;
            hL[row * 72 + col] = f2bf(v - bf2f(hi));
        }
    }

    // ---- linear2 ----
    floatx4 acc2[4] = {vzero, vzero, vzero, vzero};
    {
        const short* aH0 = hH + l15 * 72 + quad * 8;
        const short* aL0 = hL + l15 * 72 + quad * 8;
#pragma unroll
        for (int k0 = 0; k0 < 2; ++k0) {
            short8 aH = *(const short8*)(aH0 + k0 * 32);
            short8 aL = *(const short8*)(aL0 + k0 * 32);
#pragma unroll
            for (int c = 0; c < 4; ++c) {
                const int fo = ((k0 * 4 + c) * 64 + j) * 8;
                short8 bH = *(const short8*)(wH2 + fo);
                short8 bL = *(const short8*)(wL2 + fo);
                acc2[c] = __builtin_amdgcn_mfma_f32_16x16x32_bf16(aH, bH, acc2[c], 0, 0, 0);
                acc2[c] = __builtin_amdgcn_mfma_f32_16x16x32_bf16(aL, bH, acc2[c], 0, 0, 0);
                acc2[c] = __builtin_amdgcn_mfma_f32_16x16x32_bf16(aH, bL, acc2[c], 0, 0, 0);
            }
        }
    }

    // ---- epilogue ----
    if (!POOL) {
        // h1 = relu(o), fp32, row-major
#pragma unroll
        for (int c = 0; c < 4; ++c) {
            const float bv = b2[c * 16 + l15];
#pragma unroll
            for (int r = 0; r < 4; ++r) {
                const int row = wv * 16 + quad * 4 + r;
                const int node = base + row;
                if (node < N_NODES)
                    out[node * 64 + c * 16 + l15] = fmaxf(acc2[c][r] + bv, 0.f);
            }
        }
    } else {
        __syncthreads();  // all aggH reads done (oT aliases it); pooledLoc zero visible
#pragma unroll
        for (int c = 0; c < 4; ++c) {
            const float bv = b2[c * 16 + l15];
#pragma unroll
            for (int r = 0; r < 4; ++r) {
                const int row = wv * 16 + quad * 4 + r;
                U.oT[row * 66 + c * 16 + l15] = acc2[c][r] + bv;
            }
        }
        __syncthreads();
        // segmented reduce over this wave's 16 rows (batch sorted => runs)
        const int b0 = bIds[0];
        int curB = -1;
        float accv = 0.f;
        for (int r = 0; r < 16; ++r) {
            const int b = bIds[wv * 16 + r];  // wave-uniform
            if (b < 0) break;
            const float v = U.oT[(wv * 16 + r) * 66 + j];
            if (b != curB) {
                if (curB >= 0) {
                    const int s = curB - b0;
                    if (s >= 0 && s < 8) {
                        atomicAdd(&pooledLoc[s * 64 + j], accv);
                        if (j == 0) atomicMax(&maxSlot, s);
                    } else {
                        atomicAdd(&pooled[curB * 64 + j], accv);
                    }
                }
                curB = b;
                accv = v;
            } else {
                accv += v;
            }
        }
        if (curB >= 0) {
            const int s = curB - b0;
            if (s >= 0 && s < 8) {
                atomicAdd(&pooledLoc[s * 64 + j], accv);
                if (j == 0) atomicMax(&maxSlot, s);
            } else {
                atomicAdd(&pooled[curB * 64 + j], accv);
            }
        }
        __syncthreads();
        const int ns = maxSlot + 1;
        for (int s = wv; s < ns; s += 4)
            atomicAdd(&pooled[(b0 + s) * 64 + j], pooledLoc[s * 64 + j]);
    }
}

// ---------------------------------------------------------------- classifier
__global__ __launch_bounds__(64) void classifier_kernel(const float* __restrict__ pooled,
                                                        const int* __restrict__ gstart,
                                                        const float* __restrict__ wc,
                                                        const float* __restrict__ bc,
                                                        float* __restrict__ out) {
    const int g = blockIdx.x;
    const int j = threadIdx.x;
    const float c = fmaxf((float)(gstart[g + 1] - gstart[g]), 1.f);
    const float mean = pooled[g * 64 + j] / c;
#pragma unroll
    for (int cc = 0; cc < N_CLS; ++cc) {
        float p = mean * wc[j * N_CLS + cc];
#pragma unroll
        for (int off = 32; off > 0; off >>= 1) p += __shfl_down(p, off, 64);
        if (j == 0) out[g * N_CLS + cc] = p + bc[cc];
    }
}

// ---------------------------------------------------------------- launch

extern "C" void kernel_launch(void* const* d_in, const int* in_sizes, int n_in,
                              void* d_out, int out_size, void* d_ws, size_t ws_size,
                              hipStream_t stream) {
    const float* x   = (const float*)d_in[0];
    const int*   ei  = (const int*)d_in[1];
    const int* batch = (const int*)d_in[2];
    const float* w0a = (const float*)d_in[3];
    const float* b0a = (const float*)d_in[4];
    const float* g0  = (const float*)d_in[5];
    const float* be0 = (const float*)d_in[6];
    const float* m0  = (const float*)d_in[7];
    const float* v0  = (const float*)d_in[8];
    const float* w0b = (const float*)d_in[9];
    const float* b0b = (const float*)d_in[10];
    const float* w1a = (const float*)d_in[11];
    const float* b1a = (const float*)d_in[12];
    const float* g1  = (const float*)d_in[13];
    const float* be1 = (const float*)d_in[14];
    const float* m1  = (const float*)d_in[15];
    const float* v1  = (const float*)d_in[16];
    const float* w1b = (const float*)d_in[17];
    const float* b1b = (const float*)d_in[18];
    const float* wc  = (const float*)d_in[19];
    const float* bc  = (const float*)d_in[20];
    float* out = (float*)d_out;

    const int* srcI = ei;
    const int* dstI = ei + N_EDGES;

    // workspace layout, offsets in 4-byte units (16B-aligned where needed)
    int* ws = (int*)d_ws;
    int*   deg       = ws;                       // 100000
    float* pooled    = (float*)(ws + 100000);    // 32768 (contiguous with deg for zeroing)
    int*   rowptr    = ws + 132768;              // 100001
    int*   cursor    = ws + 232772;              // 100000
    int*   sortedSrc = ws + 332772;              // 1000000
    float* h1        = (float*)(ws + 1332772);   // 6400000
    float* b1p0      = (float*)(ws + 7732772);   // 64
    float* b1p1      = (float*)(ws + 7732836);   // 64
    int*   bsum      = ws + 7732900;             // 200
    int*   boff      = ws + 7733100;             // 200
    int*   gstart    = ws + 7733300;             // 513
    short* wHi       = (short*)(ws + 7733816);   // 16384 bf16
    short* wLo       = (short*)(ws + 7742008);   // 16384 bf16

    const int nz = 132768;  // deg + pooled

    // prep: zero + bounds + W pack + biases   (519*256 covers 132864)
    prep_kernel<<<519, 256, 0, stream>>>(batch, w0a, b0a, g0, be0, m0, v0, w0b,
                                         w1a, b1a, g1, be1, m1, v1, w1b,
                                         deg, nz, gstart, wHi, wLo, b1p0, b1p1);

    // CSR by dst
    hist_kernel<<<(N_EDGES + 255) / 256, 256, 0, stream>>>(dstI, deg);
    scanA_kernel<<<SCAN_NB, 256, 0, stream>>>(deg, bsum);
    scanB_kernel<<<1, 256, 0, stream>>>(bsum, boff, rowptr);
    scanC_kernel<<<SCAN_NB, 256, 0, stream>>>(deg, boff, rowptr, cursor);
    fill_kernel<<<(N_EDGES + 255) / 256, 256, 0, stream>>>(srcI, dstI, cursor, sortedSrc);

    // conv0: h1 = relu(mlp0(x + gather(x)))
    conv_mfma<0><<<NTILES, 256, 0, stream>>>(x, rowptr, sortedSrc,
                                             wHi, wLo, wHi + 4096, wLo + 4096,
                                             b1p0, b0b, h1, nullptr, nullptr);

    // conv1: pooled += mlp1(h1 + gather(h1))
    conv_mfma<1><<<NTILES, 256, 0, stream>>>(h1, rowptr, sortedSrc,
                                             wHi + 8192, wLo + 8192, wHi + 12288, wLo + 12288,
                                             b1p1, b1b, nullptr, batch, pooled);

    classifier_kernel<<<N_GRAPHS, 64, 0, stream>>>(pooled, gstart, wc, bc, out);
}

// Round 5
// 377.287 us; speedup vs baseline: 5.1419x; 1.0915x over previous
//
#include <hip/hip_runtime.h>

#define N_NODES 100000
#define N_EDGES 1000000
#define N_GRAPHS 512
#define N_CLS 10
#define BN_EPS 1e-5f

#define SCAN_NB 200   // 200 * 512 = 102400 >= N_NODES
#define NTILES 1563   // ceil(100000/64)

typedef _Float16 half8 __attribute__((ext_vector_type(8)));
typedef _Float16 half4v __attribute__((ext_vector_type(4)));
typedef _Float16 half2v __attribute__((ext_vector_type(2)));
typedef float floatx4 __attribute__((ext_vector_type(4)));

// ---------------------------------------------------------------- prep
// Fused: x->fp16 cvt | zero deg+pooled | graph bounds | W pack (f16 hi/lo MFMA B-frags) | biases
__global__ __launch_bounds__(256) void prep_kernel(
    const float* __restrict__ x, _Float16* __restrict__ xh,
    const int* __restrict__ batch,
    const float* __restrict__ w0a, const float* __restrict__ b0a,
    const float* __restrict__ g0, const float* __restrict__ be0,
    const float* __restrict__ m0, const float* __restrict__ v0,
    const float* __restrict__ w0b,
    const float* __restrict__ w1a, const float* __restrict__ b1a,
    const float* __restrict__ g1, const float* __restrict__ be1,
    const float* __restrict__ m1, const float* __restrict__ v1,
    const float* __restrict__ w1b,
    int* __restrict__ zeroBase, int nz,
    int* __restrict__ gstart,
    _Float16* __restrict__ wHi, _Float16* __restrict__ wLo,
    float* __restrict__ b1p0, float* __restrict__ b1p1) {
    const int gid = blockIdx.x * 256 + threadIdx.x;

    if (gid < 1600000) {  // x -> fp16 (6.4M elems as float4 -> half4)
        float4 v = ((const float4*)x)[gid];
        half4v h = {(_Float16)v.x, (_Float16)v.y, (_Float16)v.z, (_Float16)v.w};
        ((half4v*)xh)[gid] = h;
    }

    if (gid < nz) zeroBase[gid] = 0;

    if (gid <= N_NODES) {  // graph boundaries from sorted batch
        int bcur = (gid < N_NODES) ? batch[gid] : N_GRAPHS;
        int bprev = (gid > 0) ? batch[gid - 1] : -1;
        for (int g = bprev + 1; g <= bcur; ++g) gstart[g] = gid;
    }

    if (gid < 16384) {  // W frag pack: [mat(4)][k0(2)][c(4)][lane(64)][jj(8)]
        const int e = gid & 4095, mat = gid >> 12;
        const int jj = e & 7, lane = (e >> 3) & 63, c = (e >> 9) & 3, k0 = (e >> 11) & 1;
        const int k = k0 * 32 + (lane >> 4) * 8 + jj;
        const int col = c * 16 + (lane & 15);
        float val;
        if (mat == 0)      val = w0a[k * 64 + col] * (rsqrtf(v0[col] + BN_EPS) * g0[col]);
        else if (mat == 1) val = w0b[k * 64 + col];
        else if (mat == 2) val = w1a[k * 64 + col] * (rsqrtf(v1[col] + BN_EPS) * g1[col]);
        else               val = w1b[k * 64 + col];
        _Float16 hi = (_Float16)val;
        wHi[gid] = hi;
        wLo[gid] = (_Float16)(val - (float)hi);
    }

    if (gid >= 16384 && gid < 16512) {  // BN-folded biases
        int t = gid - 16384;
        if (t < 64) {
            float s = rsqrtf(v0[t] + BN_EPS) * g0[t];
            b1p0[t] = (b0a[t] - m0[t]) * s + be0[t];
        } else {
            t -= 64;
            float s = rsqrtf(v1[t] + BN_EPS) * g1[t];
            b1p1[t] = (b1a[t] - m1[t]) * s + be1[t];
        }
    }
}

// ---------------------------------------------------------------- CSR build
// hist also records each edge's rank within its dst bucket -> fill needs no atomics
__global__ __launch_bounds__(256) void hist_kernel(const int* __restrict__ dstI,
                                                   int* __restrict__ deg,
                                                   int* __restrict__ rank) {
    int e = blockIdx.x * 256 + threadIdx.x;
    if (e < N_EDGES) rank[e] = atomicAdd(&deg[dstI[e]], 1);
}

__global__ __launch_bounds__(256) void scanA_kernel(const int* __restrict__ deg,
                                                    int* __restrict__ bsum) {
    __shared__ int sh[256];
    const int base = blockIdx.x * 512;
    const int t = threadIdx.x;
    int a = 0, b = 0;
    if (base + t < N_NODES) a = deg[base + t];
    if (base + 256 + t < N_NODES) b = deg[base + 256 + t];
    sh[t] = a + b;
    __syncthreads();
#pragma unroll
    for (int off = 128; off > 0; off >>= 1) {
        if (t < off) sh[t] += sh[t + off];
        __syncthreads();
    }
    if (t == 0) bsum[blockIdx.x] = sh[0];
}

__global__ __launch_bounds__(256) void scanB_kernel(const int* __restrict__ bsum,
                                                    int* __restrict__ boff,
                                                    int* __restrict__ rowptr) {
    __shared__ int sh[256];
    const int t = threadIdx.x;
    const int v = (t < SCAN_NB) ? bsum[t] : 0;
    sh[t] = v;
    __syncthreads();
#pragma unroll
    for (int off = 1; off < 256; off <<= 1) {
        int u = (t >= off) ? sh[t - off] : 0;
        __syncthreads();
        sh[t] += u;
        __syncthreads();
    }
    if (t < SCAN_NB) boff[t] = sh[t] - v;
    if (t == 0) rowptr[N_NODES] = N_EDGES;
}

__global__ __launch_bounds__(256) void scanC_kernel(const int* __restrict__ deg,
                                                    const int* __restrict__ boff,
                                                    int* __restrict__ rowptr) {
    __shared__ int sh[256];
    const int base = blockIdx.x * 512;
    const int t = threadIdx.x;
    const int i0 = base + 2 * t, i1 = i0 + 1;
    const int d0 = (i0 < N_NODES) ? deg[i0] : 0;
    const int d1 = (i1 < N_NODES) ? deg[i1] : 0;
    const int p = d0 + d1;
    sh[t] = p;
    __syncthreads();
#pragma unroll
    for (int off = 1; off < 256; off <<= 1) {
        int u = (t >= off) ? sh[t - off] : 0;
        __syncthreads();
        sh[t] += u;
        __syncthreads();
    }
    const int excl = boff[blockIdx.x] + sh[t] - p;
    if (i0 < N_NODES) rowptr[i0] = excl;
    if (i1 < N_NODES) rowptr[i1] = excl + d0;
}

__global__ __launch_bounds__(256) void fill_kernel(const int* __restrict__ srcI,
                                                   const int* __restrict__ dstI,
                                                   const int* __restrict__ rank,
                                                   const int* __restrict__ rowptr,
                                                   int* __restrict__ sortedSrc) {
    int e = blockIdx.x * 256 + threadIdx.x;
    if (e >= N_EDGES) return;
    sortedSrc[rowptr[dstI[e]] + rank[e]] = srcI[e];
}

// ---------------------------------------------------------------- fused conv (MFMA, fp16)
// Block = 256 thr = 4 waves, 64-node tile. Wave = 2 groups of 32 lanes; each group
// gathers one edge row per request (half2/lane, 256B per instr for 2 edges).
// Agg in fp32, split f16 hi/lo -> 3-MFMA per linear (f32_16x16x32_f16).
// 16x16x32 layouts: A[m=lane&15][k=(lane>>4)*8+jj]; B[k][n=lane&15]; C/D: col=lane&15,
// row=(lane>>4)*4+reg.
template <int POOL>
__global__ __launch_bounds__(256) void conv_mfma(
    const _Float16* __restrict__ in, const int* __restrict__ rowptr,
    const int* __restrict__ srcList,
    const _Float16* __restrict__ wH1, const _Float16* __restrict__ wL1,
    const _Float16* __restrict__ wH2, const _Float16* __restrict__ wL2,
    const float* __restrict__ b1, const float* __restrict__ b2,
    _Float16* __restrict__ out, const int* __restrict__ batch,
    float* __restrict__ pooled) {
    __shared__ __align__(16) union SM {
        struct { _Float16 aggH[64 * 72]; _Float16 aggL[64 * 72]; } a;  // 18432 B
        float oT[64 * 66];                                             // 16896 B
    } U;
    __shared__ __align__(16) _Float16 hBuf[4][2 * 1152];
    __shared__ float pooledLoc[8 * 64];
    __shared__ int bIds[64];
    __shared__ int maxSlot;

    const int tid = threadIdx.x;
    const int j = tid & 63, wv = tid >> 6;
    const int l = j & 31, grp = j >> 5;
    const int base = blockIdx.x * 64;

    if (POOL) {
        pooledLoc[tid] = 0.f;
        pooledLoc[tid + 256] = 0.f;
        if (tid == 0) maxSlot = 0;
    }

#define GATH(A, S)                                                        \
    {                                                                     \
        half2v hv = *(const half2v*)(in + (size_t)(S) * 64 + 2 * l);      \
        A.x += (float)hv.x;                                               \
        A.y += (float)hv.y;                                               \
    }

    // ---- gather-aggregate into LDS ----
    for (int m = 0; m < 16; ++m) {
        const int ml = wv * 16 + m;
        const int node = base + ml;
        float2 a0 = {0.f, 0.f}, a1 = {0.f, 0.f}, a2 = {0.f, 0.f}, a3 = {0.f, 0.f};
        float2 a4 = {0.f, 0.f}, a5 = {0.f, 0.f}, a6 = {0.f, 0.f}, a7 = {0.f, 0.f};
        if (node < N_NODES) {
            const int nu = __builtin_amdgcn_readfirstlane(node);
            if (grp == 0) GATH(a0, nu);  // self (GIN eps=0), group0 only
            const int r0 = __builtin_amdgcn_readfirstlane(rowptr[nu]);
            const int r1 = __builtin_amdgcn_readfirstlane(rowptr[nu + 1]);
            for (int eb = r0; eb < r1; eb += 64) {
                const int cnt = min(64, r1 - eb);
                const int vsrc = (eb + j < r1) ? srcList[eb + j] : 0;
                const int pairs = cnt >> 1;
                int i = 0;
#define PAIRSEL(ii)                                                          \
    int sa##ii = __builtin_amdgcn_readlane(vsrc, 2 * (i + ii));              \
    int sb##ii = __builtin_amdgcn_readlane(vsrc, 2 * (i + ii) + 1);          \
    int s##ii = grp ? sb##ii : sa##ii;
                for (; i + 8 <= pairs; i += 8) {
                    PAIRSEL(0) PAIRSEL(1) PAIRSEL(2) PAIRSEL(3)
                    PAIRSEL(4) PAIRSEL(5) PAIRSEL(6) PAIRSEL(7)
                    GATH(a0, s0) GATH(a1, s1) GATH(a2, s2) GATH(a3, s3)
                    GATH(a4, s4) GATH(a5, s5) GATH(a6, s6) GATH(a7, s7)
                }
                for (; i < pairs; ++i) {
                    PAIRSEL(0)
                    GATH(a0, s0)
                }
                if (cnt & 1) {
                    int s = __builtin_amdgcn_readlane(vsrc, cnt - 1);
                    if (grp == 0) GATH(a1, s)
                }
            }
            if (POOL && j == 0) bIds[ml] = batch[nu];
        } else {
            if (POOL && j == 0) bIds[ml] = -1;
        }
        float fx = ((a0.x + a1.x) + (a2.x + a3.x)) + ((a4.x + a5.x) + (a6.x + a7.x));
        float fy = ((a0.y + a1.y) + (a2.y + a3.y)) + ((a4.y + a5.y) + (a6.y + a7.y));
        fx += __shfl_xor(fx, 32, 64);  // cross-group combine
        fy += __shfl_xor(fy, 32, 64);
        if (grp == 0) {  // lane l owns features 2l, 2l+1
            _Float16 hx = (_Float16)fx, hy = (_Float16)fy;
            half2v hi = {hx, hy};
            half2v lo = {(_Float16)(fx - (float)hx), (_Float16)(fy - (float)hy)};
            *(half2v*)(&U.a.aggH[ml * 72 + 2 * l]) = hi;
            *(half2v*)(&U.a.aggL[ml * 72 + 2 * l]) = lo;
        }
    }
#undef PAIRSEL
#undef GATH
    __syncthreads();

    const int l15 = j & 15, quad = j >> 4;
    const floatx4 vzero = {0.f, 0.f, 0.f, 0.f};

    // ---- linear1 (+BN fold) ----
    floatx4 acc[4] = {vzero, vzero, vzero, vzero};
    {
        const _Float16* aH0 = U.a.aggH + (wv * 16 + l15) * 72 + quad * 8;
        const _Float16* aL0 = U.a.aggL + (wv * 16 + l15) * 72 + quad * 8;
#pragma unroll
        for (int k0 = 0; k0 < 2; ++k0) {
            half8 aH = *(const half8*)(aH0 + k0 * 32);
            half8 aL = *(const half8*)(aL0 + k0 * 32);
#pragma unroll
            for (int c = 0; c < 4; ++c) {
                const int fo = ((k0 * 4 + c) * 64 + j) * 8;
                half8 bH = *(const half8*)(wH1 + fo);
                half8 bL = *(const half8*)(wL1 + fo);
                acc[c] = __builtin_amdgcn_mfma_f32_16x16x32_f16(aH, bH, acc[c], 0, 0, 0);
                acc[c] = __builtin_amdgcn_mfma_f32_16x16x32_f16(aL, bH, acc[c], 0, 0, 0);
                acc[c] = __builtin_amdgcn_mfma_f32_16x16x32_f16(aH, bL, acc[c], 0, 0, 0);
            }
        }
    }
    // bias + relu + split into per-wave H strip
    _Float16* hH = hBuf[wv];
    _Float16* hL = hH + 1152;
#pragma unroll
    for (int c = 0; c < 4; ++c) {
        const float bv = b1[c * 16 + l15];
#pragma unroll
        for (int r = 0; r < 4; ++r) {
            const int row = quad * 4 + r, col = c * 16 + l15;
            float v = acc[c][r] + bv;
            v = fmaxf(v, 0.f);
            const _Float16 hi = (_Float16)v;
            hH[row * 72 + col] = hi;
            hL[row * 72 + col] = (_Float16)(v - (float)hi);
        }
    }

    // ---- linear2 ----
    floatx4 acc2[4] = {vzero, vzero, vzero, vzero};
    {
        const _Float16* aH0 = hH + l15 * 72 + quad * 8;
        const _Float16* aL0 = hL + l15 * 72 + quad * 8;
#pragma unroll
        for (int k0 = 0; k0 < 2; ++k0) {
            half8 aH = *(const half8*)(aH0 + k0 * 32);
            half8 aL = *(const half8*)(aL0 + k0 * 32);
#pragma unroll
            for (int c = 0; c < 4; ++c) {
                const int fo = ((k0 * 4 + c) * 64 + j) * 8;
                half8 bH = *(const half8*)(wH2 + fo);
                half8 bL = *(const half8*)(wL2 + fo);
                acc2[c] = __builtin_amdgcn_mfma_f32_16x16x32_f16(aH, bH, acc2[c], 0, 0, 0);
                acc2[c] = __builtin_amdgcn_mfma_f32_16x16x32_f16(aL, bH, acc2[c], 0, 0, 0);
                acc2[c] = __builtin_amdgcn_mfma_f32_16x16x32_f16(aH, bL, acc2[c], 0, 0, 0);
            }
        }
    }

    // ---- epilogue ----
    if (!POOL) {
        // h1 = relu(o), fp16, row-major
#pragma unroll
        for (int c = 0; c < 4; ++c) {
            const float bv = b2[c * 16 + l15];
#pragma unroll
            for (int r = 0; r < 4; ++r) {
                const int row = wv * 16 + quad * 4 + r;
                const int node = base + row;
                if (node < N_NODES)
                    out[(size_t)node * 64 + c * 16 + l15] =
                        (_Float16)fmaxf(acc2[c][r] + bv, 0.f);
            }
        }
    } else {
        __syncthreads();  // agg reads done (oT aliases agg)
#pragma unroll
        for (int c = 0; c < 4; ++c) {
            const float bv = b2[c * 16 + l15];
#pragma unroll
            for (int r = 0; r < 4; ++r) {
                const int row = wv * 16 + quad * 4 + r;
                U.oT[row * 66 + c * 16 + l15] = acc2[c][r] + bv;
            }
        }
        __syncthreads();
        // segmented reduce over this wave's 16 rows (batch sorted => runs)
        const int b0 = bIds[0];
        int curB = -1;
        float accv = 0.f;
        for (int r = 0; r < 16; ++r) {
            const int b = bIds[wv * 16 + r];  // wave-uniform
            if (b < 0) break;
            const float v = U.oT[(wv * 16 + r) * 66 + j];
            if (b != curB) {
                if (curB >= 0) {
                    const int s = curB - b0;
                    if (s >= 0 && s < 8) {
                        atomicAdd(&pooledLoc[s * 64 + j], accv);
                        if (j == 0) atomicMax(&maxSlot, s);
                    } else {
                        atomicAdd(&pooled[curB * 64 + j], accv);
                    }
                }
                curB = b;
                accv = v;
            } else {
                accv += v;
            }
        }
        if (curB >= 0) {
            const int s = curB - b0;
            if (s >= 0 && s < 8) {
                atomicAdd(&pooledLoc[s * 64 + j], accv);
                if (j == 0) atomicMax(&maxSlot, s);
            } else {
                atomicAdd(&pooled[curB * 64 + j], accv);
            }
        }
        __syncthreads();
        const int ns = maxSlot + 1;
        for (int s = wv; s < ns; s += 4)
            atomicAdd(&pooled[(b0 + s) * 64 + j], pooledLoc[s * 64 + j]);
    }
}

// ---------------------------------------------------------------- classifier
__global__ __launch_bounds__(64) void classifier_kernel(const float* __restrict__ pooled,
                                                        const int* __restrict__ gstart,
                                                        const float* __restrict__ wc,
                                                        const float* __restrict__ bc,
                                                        float* __restrict__ out) {
    const int g = blockIdx.x;
    const int j = threadIdx.x;
    const float c = fmaxf((float)(gstart[g + 1] - gstart[g]), 1.f);
    const float mean = pooled[g * 64 + j] / c;
#pragma unroll
    for (int cc = 0; cc < N_CLS; ++cc) {
        float p = mean * wc[j * N_CLS + cc];
#pragma unroll
        for (int off = 32; off > 0; off >>= 1) p += __shfl_down(p, off, 64);
        if (j == 0) out[g * N_CLS + cc] = p + bc[cc];
    }
}

// ---------------------------------------------------------------- launch

extern "C" void kernel_launch(void* const* d_in, const int* in_sizes, int n_in,
                              void* d_out, int out_size, void* d_ws, size_t ws_size,
                              hipStream_t stream) {
    const float* x   = (const float*)d_in[0];
    const int*   ei  = (const int*)d_in[1];
    const int* batch = (const int*)d_in[2];
    const float* w0a = (const float*)d_in[3];
    const float* b0a = (const float*)d_in[4];
    const float* g0  = (const float*)d_in[5];
    const float* be0 = (const float*)d_in[6];
    const float* m0  = (const float*)d_in[7];
    const float* v0  = (const float*)d_in[8];
    const float* w0b = (const float*)d_in[9];
    const float* b0b = (const float*)d_in[10];
    const float* w1a = (const float*)d_in[11];
    const float* b1a = (const float*)d_in[12];
    const float* g1  = (const float*)d_in[13];
    const float* be1 = (const float*)d_in[14];
    const float* m1  = (const float*)d_in[15];
    const float* v1  = (const float*)d_in[16];
    const float* w1b = (const float*)d_in[17];
    const float* b1b = (const float*)d_in[18];
    const float* wc  = (const float*)d_in[19];
    const float* bc  = (const float*)d_in[20];
    float* out = (float*)d_out;

    const int* srcI = ei;
    const int* dstI = ei + N_EDGES;

    // workspace layout, offsets in 4-byte units (16B-aligned where needed)
    int* ws = (int*)d_ws;
    int*      deg       = ws;                            // 100000
    float*    pooled    = (float*)(ws + 100000);         // 32768 (contig w/ deg for zeroing)
    int*      rowptr    = ws + 132768;                   // 100001
    int*      rank      = ws + 232772;                   // 1000000
    int*      sortedSrc = ws + 1232772;                  // 1000000
    _Float16* xh        = (_Float16*)(ws + 2232772);     // 6400000 halves
    _Float16* h1        = (_Float16*)(ws + 5432772);     // 6400000 halves
    float*    b1p0      = (float*)(ws + 8632772);        // 64
    float*    b1p1      = (float*)(ws + 8632836);        // 64
    int*      bsum      = ws + 8632900;                  // 200
    int*      boff      = ws + 8633100;                  // 200
    int*      gstart    = ws + 8633300;                  // 513
    _Float16* wHi       = (_Float16*)(ws + 8633816);     // 16384 halves
    _Float16* wLo       = (_Float16*)(ws + 8642008);     // 16384 halves
    // total ~34.6 MB

    const int nz = 132768;  // deg + pooled

    // prep: x->f16 + zero + bounds + W pack + biases
    prep_kernel<<<6250, 256, 0, stream>>>(x, xh, batch,
                                          w0a, b0a, g0, be0, m0, v0, w0b,
                                          w1a, b1a, g1, be1, m1, v1, w1b,
                                          deg, nz, gstart, wHi, wLo, b1p0, b1p1);

    // CSR by dst (rank-based, no fill atomics)
    hist_kernel<<<(N_EDGES + 255) / 256, 256, 0, stream>>>(dstI, deg, rank);
    scanA_kernel<<<SCAN_NB, 256, 0, stream>>>(deg, bsum);
    scanB_kernel<<<1, 256, 0, stream>>>(bsum, boff, rowptr);
    scanC_kernel<<<SCAN_NB, 256, 0, stream>>>(deg, boff, rowptr);
    fill_kernel<<<(N_EDGES + 255) / 256, 256, 0, stream>>>(srcI, dstI, rank, rowptr, sortedSrc);

    // conv0: h1 = relu(mlp0(x + gather(x)))   [fp16 features]
    conv_mfma<0><<<NTILES, 256, 0, stream>>>(xh, rowptr, sortedSrc,
                                             wHi, wLo, wHi + 4096, wLo + 4096,
                                             b1p0, b0b, h1, nullptr, nullptr);

    // conv1: pooled += mlp1(h1 + gather(h1))
    conv_mfma<1><<<NTILES, 256, 0, stream>>>(h1, rowptr, sortedSrc,
                                             wHi + 8192, wLo + 8192, wHi + 12288, wLo + 12288,
                                             b1p1, b1b, nullptr, batch, pooled);

    classifier_kernel<<<N_GRAPHS, 64, 0, stream>>>(pooled, gstart, wc, bc, out);
}

// Round 6
// 353.307 us; speedup vs baseline: 5.4909x; 1.0679x over previous
//
#include <hip/hip_runtime.h>

#define N_NODES 100000
#define N_EDGES 1000000
#define N_GRAPHS 512
#define N_CLS 10
#define BN_EPS 1e-5f

#define SCAN_NB 200   // 200 * 512 = 102400 >= N_NODES
#define NTILES 1563   // ceil(100000/64)
#define SCHUNK 320    // per-wave staged src ids (strip slice ~Poisson(160); fallback if over)

typedef _Float16 half8 __attribute__((ext_vector_type(8)));
typedef _Float16 half4v __attribute__((ext_vector_type(4)));
typedef _Float16 half2v __attribute__((ext_vector_type(2)));
typedef float floatx4 __attribute__((ext_vector_type(4)));

// ---------------------------------------------------------------- prep
// Fused: x->fp16 | deg-hist+rank | graph bounds | W pack (f16 hi/lo B-frags) | biases.
// deg+pooled are zeroed by hipMemsetAsync before this kernel.
__global__ __launch_bounds__(256) void prep_kernel(
    const float* __restrict__ x, _Float16* __restrict__ xh,
    const int* __restrict__ batch, const int* __restrict__ dstI,
    int* __restrict__ deg, int* __restrict__ rank,
    const float* __restrict__ w0a, const float* __restrict__ b0a,
    const float* __restrict__ g0, const float* __restrict__ be0,
    const float* __restrict__ m0, const float* __restrict__ v0,
    const float* __restrict__ w0b,
    const float* __restrict__ w1a, const float* __restrict__ b1a,
    const float* __restrict__ g1, const float* __restrict__ be1,
    const float* __restrict__ m1, const float* __restrict__ v1,
    const float* __restrict__ w1b,
    int* __restrict__ gstart,
    _Float16* __restrict__ wHi, _Float16* __restrict__ wLo,
    float* __restrict__ b1p0, float* __restrict__ b1p1) {
    const int gid = blockIdx.x * 256 + threadIdx.x;

    if (gid < 1600000) {  // x -> fp16 (6.4M elems as float4 -> half4)
        float4 v = ((const float4*)x)[gid];
        half4v h = {(_Float16)v.x, (_Float16)v.y, (_Float16)v.z, (_Float16)v.w};
        ((half4v*)xh)[gid] = h;
    }

    if (gid < N_EDGES)  // histogram + per-edge rank within dst bucket
        rank[gid] = atomicAdd(&deg[dstI[gid]], 1);

    if (gid <= N_NODES) {  // graph boundaries from sorted batch
        int bcur = (gid < N_NODES) ? batch[gid] : N_GRAPHS;
        int bprev = (gid > 0) ? batch[gid - 1] : -1;
        for (int g = bprev + 1; g <= bcur; ++g) gstart[g] = gid;
    }

    if (gid < 16384) {  // W frag pack: [mat(4)][k0(2)][c(4)][lane(64)][jj(8)]
        const int e = gid & 4095, mat = gid >> 12;
        const int jj = e & 7, lane = (e >> 3) & 63, c = (e >> 9) & 3, k0 = (e >> 11) & 1;
        const int k = k0 * 32 + (lane >> 4) * 8 + jj;
        const int col = c * 16 + (lane & 15);
        float val;
        if (mat == 0)      val = w0a[k * 64 + col] * (rsqrtf(v0[col] + BN_EPS) * g0[col]);
        else if (mat == 1) val = w0b[k * 64 + col];
        else if (mat == 2) val = w1a[k * 64 + col] * (rsqrtf(v1[col] + BN_EPS) * g1[col]);
        else               val = w1b[k * 64 + col];
        _Float16 hi = (_Float16)val;
        wHi[gid] = hi;
        wLo[gid] = (_Float16)(val - (float)hi);
    }

    if (gid >= 16384 && gid < 16512) {  // BN-folded biases
        int t = gid - 16384;
        if (t < 64) {
            float s = rsqrtf(v0[t] + BN_EPS) * g0[t];
            b1p0[t] = (b0a[t] - m0[t]) * s + be0[t];
        } else {
            t -= 64;
            float s = rsqrtf(v1[t] + BN_EPS) * g1[t];
            b1p1[t] = (b1a[t] - m1[t]) * s + be1[t];
        }
    }
}

// ---------------------------------------------------------------- scans
__global__ __launch_bounds__(256) void scanA_kernel(const int* __restrict__ deg,
                                                    int* __restrict__ bsum) {
    __shared__ int sh[256];
    const int base = blockIdx.x * 512;
    const int t = threadIdx.x;
    int a = 0, b = 0;
    if (base + t < N_NODES) a = deg[base + t];
    if (base + 256 + t < N_NODES) b = deg[base + 256 + t];
    sh[t] = a + b;
    __syncthreads();
#pragma unroll
    for (int off = 128; off > 0; off >>= 1) {
        if (t < off) sh[t] += sh[t + off];
        __syncthreads();
    }
    if (t == 0) bsum[blockIdx.x] = sh[0];
}

__global__ __launch_bounds__(256) void scanB_kernel(const int* __restrict__ bsum,
                                                    int* __restrict__ boff,
                                                    int* __restrict__ rowptr) {
    __shared__ int sh[256];
    const int t = threadIdx.x;
    const int v = (t < SCAN_NB) ? bsum[t] : 0;
    sh[t] = v;
    __syncthreads();
#pragma unroll
    for (int off = 1; off < 256; off <<= 1) {
        int u = (t >= off) ? sh[t - off] : 0;
        __syncthreads();
        sh[t] += u;
        __syncthreads();
    }
    if (t < SCAN_NB) boff[t] = sh[t] - v;
    if (t == 0) rowptr[N_NODES] = N_EDGES;
}

__global__ __launch_bounds__(256) void scanC_kernel(const int* __restrict__ deg,
                                                    const int* __restrict__ boff,
                                                    int* __restrict__ rowptr) {
    __shared__ int sh[256];
    const int base = blockIdx.x * 512;
    const int t = threadIdx.x;
    const int i0 = base + 2 * t, i1 = i0 + 1;
    const int d0 = (i0 < N_NODES) ? deg[i0] : 0;
    const int d1 = (i1 < N_NODES) ? deg[i1] : 0;
    const int p = d0 + d1;
    sh[t] = p;
    __syncthreads();
#pragma unroll
    for (int off = 1; off < 256; off <<= 1) {
        int u = (t >= off) ? sh[t - off] : 0;
        __syncthreads();
        sh[t] += u;
        __syncthreads();
    }
    const int excl = boff[blockIdx.x] + sh[t] - p;
    if (i0 < N_NODES) rowptr[i0] = excl;
    if (i1 < N_NODES) rowptr[i1] = excl + d0;
}

__global__ __launch_bounds__(256) void fill_kernel(const int* __restrict__ srcI,
                                                   const int* __restrict__ dstI,
                                                   const int* __restrict__ rank,
                                                   const int* __restrict__ rowptr,
                                                   int* __restrict__ sortedSrc) {
    int e = blockIdx.x * 256 + threadIdx.x;
    if (e >= N_EDGES) return;
    sortedSrc[rowptr[dstI[e]] + rank[e]] = srcI[e];
}

// ---------------------------------------------------------------- fused conv (MFMA, fp16)
// Block = 4 waves x 16-node strips. Per wave: rowptr strip preloaded to a VGPR
// (readlane per row), CSR slice staged to LDS once (contiguous, dst-sorted),
// per row up to 8 edge-pairs issued under UNIFORM guards into separate temps so
// all global loads stay in flight (one vmcnt wait per 16 edges, not per pair).
// Wave = 2x32-lane groups; each 4B load covers 2 halves => 2 edges per instr.
// MLP: split-f16 3-MFMA per linear; all big LDS is wave-private and reused
// (agg -> H -> oT) => ~26KB/block, 6 blocks/CU.
template <int POOL>
__global__ __launch_bounds__(256) void conv_mfma(
    const _Float16* __restrict__ in, const int* __restrict__ rowptr,
    const int* __restrict__ srcList,
    const _Float16* __restrict__ wH1, const _Float16* __restrict__ wL1,
    const _Float16* __restrict__ wH2, const _Float16* __restrict__ wL2,
    const float* __restrict__ b1, const float* __restrict__ b2,
    _Float16* __restrict__ out, const int* __restrict__ batch,
    float* __restrict__ pooled) {
    __shared__ __align__(16) _Float16 scratch[4][2304];  // per-wave: aggH|aggL -> hH|hL -> oT
    __shared__ int ldsSrc[4][SCHUNK];
    __shared__ float pooledLoc[8 * 64];
    __shared__ int bIds[64];
    __shared__ int maxSlot;

    const int tid = threadIdx.x;
    const int j = tid & 63, wv = tid >> 6;
    const int l = j & 31, grp = j >> 5;
    const int base = blockIdx.x * 64;
    const int strip0 = base + wv * 16;

    if (POOL) {
        pooledLoc[tid] = 0.f;
        pooledLoc[tid + 256] = 0.f;
        if (tid == 0) maxSlot = 0;
        if (j < 16) {
            int node = strip0 + j;
            bIds[wv * 16 + j] = (node < N_NODES) ? batch[node] : -1;
        }
    }

    // rowptr strip (17 values) in one vector load; broadcast later via readlane
    const int rpv = rowptr[min(strip0 + min(j, 16), N_NODES)];
    const int sliceStart = __builtin_amdgcn_readlane(rpv, 0);
    const int sliceEnd = __builtin_amdgcn_readlane(rpv, 16);
    const int sliceLen = sliceEnd - sliceStart;

    // stage this wave's CSR slice into LDS (coalesced; ~160 edges avg)
    for (int i = j; i < sliceLen && i < SCHUNK; i += 64)
        ldsSrc[wv][i] = srcList[sliceStart + i];

    _Float16* aggH = scratch[wv];
    _Float16* aggL = scratch[wv] + 1152;

    for (int m = 0; m < 16; ++m) {
        const int node = strip0 + m;  // wave-uniform
        if (node >= N_NODES) break;
        const int r0 = __builtin_amdgcn_readlane(rpv, m);
        const int r1 = __builtin_amdgcn_readlane(rpv, m + 1);
        const int cnt = r1 - r0;
        const int r0loc = r0 - sliceStart;

        float2 a0 = {0, 0}, a1 = {0, 0}, a2 = {0, 0}, a3 = {0, 0};
        float2 a4 = {0, 0}, a5 = {0, 0}, a6 = {0, 0}, a7 = {0, 0};

        half2v vself = {0, 0};
        if (grp == 0) vself = *(const half2v*)(in + (size_t)node * 64 + 2 * l);

        for (int eb = 0; eb < cnt; eb += 16) {
            const int c = min(cnt - eb, 16);
            const int idbase = r0loc + eb;
            int idvec;
            if (idbase + 16 <= SCHUNK)
                idvec = ldsSrc[wv][idbase + (j & 15)];
            else
                idvec = srcList[min(sliceStart + idbase + (j & 15), N_EDGES - 1)];
            const int pairs_u = c >> 1;

            half2v v0 = {0, 0}, v1 = {0, 0}, v2 = {0, 0}, v3 = {0, 0};
            half2v v4 = {0, 0}, v5 = {0, 0}, v6 = {0, 0}, v7 = {0, 0};
            half2v vodd = {0, 0};
#define ISSUE(K)                                                              \
    if (K < pairs_u) {                                                        \
        int sa = __builtin_amdgcn_readlane(idvec, 2 * K);                     \
        int sb = __builtin_amdgcn_readlane(idvec, 2 * K + 1);                 \
        int s = grp ? sb : sa;                                                \
        v##K = *(const half2v*)(in + (size_t)s * 64 + 2 * l);                 \
    }
            ISSUE(0) ISSUE(1) ISSUE(2) ISSUE(3) ISSUE(4) ISSUE(5) ISSUE(6) ISSUE(7)
#undef ISSUE
            if (c & 1) {
                int s = __builtin_amdgcn_readlane(idvec, c - 1);
                if (grp == 0) vodd = *(const half2v*)(in + (size_t)s * 64 + 2 * l);
            }
            a0.x += (float)v0.x; a0.y += (float)v0.y;
            a1.x += (float)v1.x; a1.y += (float)v1.y;
            a2.x += (float)v2.x; a2.y += (float)v2.y;
            a3.x += (float)v3.x; a3.y += (float)v3.y;
            a4.x += (float)v4.x; a4.y += (float)v4.y;
            a5.x += (float)v5.x; a5.y += (float)v5.y;
            a6.x += (float)v6.x; a6.y += (float)v6.y;
            a7.x += (float)v7.x; a7.y += (float)v7.y;
            a1.x += (float)vodd.x; a1.y += (float)vodd.y;
        }
        a0.x += (float)vself.x; a0.y += (float)vself.y;

        float fx = ((a0.x + a1.x) + (a2.x + a3.x)) + ((a4.x + a5.x) + (a6.x + a7.x));
        float fy = ((a0.y + a1.y) + (a2.y + a3.y)) + ((a4.y + a5.y) + (a6.y + a7.y));
        fx += __shfl_xor(fx, 32, 64);
        fy += __shfl_xor(fy, 32, 64);
        if (grp == 0) {
            _Float16 hx = (_Float16)fx, hy = (_Float16)fy;
            *(half2v*)(aggH + m * 72 + 2 * l) = (half2v){hx, hy};
            *(half2v*)(aggL + m * 72 + 2 * l) =
                (half2v){(_Float16)(fx - (float)hx), (_Float16)(fy - (float)hy)};
        }
    }

    const int l15 = j & 15, quad = j >> 4;
    const floatx4 vzero = {0.f, 0.f, 0.f, 0.f};

    // ---- linear1 (+BN fold) ----   (A rows are wave-private: no barrier needed)
    floatx4 acc[4] = {vzero, vzero, vzero, vzero};
    {
        const _Float16* aH0 = aggH + l15 * 72 + quad * 8;
        const _Float16* aL0 = aggL + l15 * 72 + quad * 8;
#pragma unroll
        for (int k0 = 0; k0 < 2; ++k0) {
            half8 aH = *(const half8*)(aH0 + k0 * 32);
            half8 aL = *(const half8*)(aL0 + k0 * 32);
#pragma unroll
            for (int c = 0; c < 4; ++c) {
                const int fo = ((k0 * 4 + c) * 64 + j) * 8;
                half8 bH = *(const half8*)(wH1 + fo);
                half8 bL = *(const half8*)(wL1 + fo);
                acc[c] = __builtin_amdgcn_mfma_f32_16x16x32_f16(aH, bH, acc[c], 0, 0, 0);
                acc[c] = __builtin_amdgcn_mfma_f32_16x16x32_f16(aL, bH, acc[c], 0, 0, 0);
                acc[c] = __builtin_amdgcn_mfma_f32_16x16x32_f16(aH, bL, acc[c], 0, 0, 0);
            }
        }
    }
    // bias + relu + split H back into the SAME wave-private scratch (agg reads done)
    _Float16* hH = aggH;
    _Float16* hL = aggL;
#pragma unroll
    for (int c = 0; c < 4; ++c) {
        const float bv = b1[c * 16 + l15];
#pragma unroll
        for (int r = 0; r < 4; ++r) {
            const int row = quad * 4 + r, col = c * 16 + l15;
            float v = acc[c][r] + bv;
            v = fmaxf(v, 0.f);
            const _Float16 hi = (_Float16)v;
            hH[row * 72 + col] = hi;
            hL[row * 72 + col] = (_Float16)(v - (float)hi);
        }
    }

    // ---- linear2 ----
    floatx4 acc2[4] = {vzero, vzero, vzero, vzero};
    {
        const _Float16* aH0 = hH + l15 * 72 + quad * 8;
        const _Float16* aL0 = hL + l15 * 72 + quad * 8;
#pragma unroll
        for (int k0 = 0; k0 < 2; ++k0) {
            half8 aH = *(const half8*)(aH0 + k0 * 32);
            half8 aL = *(const half8*)(aL0 + k0 * 32);
#pragma unroll
            for (int c = 0; c < 4; ++c) {
                const int fo = ((k0 * 4 + c) * 64 + j) * 8;
                half8 bH = *(const half8*)(wH2 + fo);
                half8 bL = *(const half8*)(wL2 + fo);
                acc2[c] = __builtin_amdgcn_mfma_f32_16x16x32_f16(aH, bH, acc2[c], 0, 0, 0);
                acc2[c] = __builtin_amdgcn_mfma_f32_16x16x32_f16(aL, bH, acc2[c], 0, 0, 0);
                acc2[c] = __builtin_amdgcn_mfma_f32_16x16x32_f16(aH, bL, acc2[c], 0, 0, 0);
            }
        }
    }

    // ---- epilogue ----
    if (!POOL) {
#pragma unroll
        for (int c = 0; c < 4; ++c) {
            const float bv = b2[c * 16 + l15];
#pragma unroll
            for (int r = 0; r < 4; ++r) {
                const int node = strip0 + quad * 4 + r;
                if (node < N_NODES)
                    out[(size_t)node * 64 + c * 16 + l15] =
                        (_Float16)fmaxf(acc2[c][r] + bv, 0.f);
            }
        }
    } else {
        float* oT = (float*)scratch[wv];  // 16 x 66, wave-private (hBuf reads done)
#pragma unroll
        for (int c = 0; c < 4; ++c) {
            const float bv = b2[c * 16 + l15];
#pragma unroll
            for (int r = 0; r < 4; ++r)
                oT[(quad * 4 + r) * 66 + c * 16 + l15] = acc2[c][r] + bv;
        }
        __syncthreads();  // bIds[0] + pooledLoc zeros visible; oT is own-wave
        const int b0 = bIds[0];
        int curB = -1;
        float accv = 0.f;
        for (int r = 0; r < 16; ++r) {
            const int b = bIds[wv * 16 + r];  // wave-uniform
            if (b < 0) break;
            const float v = oT[r * 66 + j];
            if (b != curB) {
                if (curB >= 0) {
                    const int s = curB - b0;
                    if (s >= 0 && s < 8) {
                        atomicAdd(&pooledLoc[s * 64 + j], accv);
                        if (j == 0) atomicMax(&maxSlot, s);
                    } else {
                        atomicAdd(&pooled[curB * 64 + j], accv);
                    }
                }
                curB = b;
                accv = v;
            } else {
                accv += v;
            }
        }
        if (curB >= 0) {
            const int s = curB - b0;
            if (s >= 0 && s < 8) {
                atomicAdd(&pooledLoc[s * 64 + j], accv);
                if (j == 0) atomicMax(&maxSlot, s);
            } else {
                atomicAdd(&pooled[curB * 64 + j], accv);
            }
        }
        __syncthreads();
        const int ns = maxSlot + 1;
        for (int s = wv; s < ns; s += 4)
            atomicAdd(&pooled[(b0 + s) * 64 + j], pooledLoc[s * 64 + j]);
    }
}

// ---------------------------------------------------------------- classifier
__global__ __launch_bounds__(64) void classifier_kernel(const float* __restrict__ pooled,
                                                        const int* __restrict__ gstart,
                                                        const float* __restrict__ wc,
                                                        const float* __restrict__ bc,
                                                        float* __restrict__ out) {
    const int g = blockIdx.x;
    const int j = threadIdx.x;
    const float c = fmaxf((float)(gstart[g + 1] - gstart[g]), 1.f);
    const float mean = pooled[g * 64 + j] / c;
#pragma unroll
    for (int cc = 0; cc < N_CLS; ++cc) {
        float p = mean * wc[j * N_CLS + cc];
#pragma unroll
        for (int off = 32; off > 0; off >>= 1) p += __shfl_down(p, off, 64);
        if (j == 0) out[g * N_CLS + cc] = p + bc[cc];
    }
}

// ---------------------------------------------------------------- launch

extern "C" void kernel_launch(void* const* d_in, const int* in_sizes, int n_in,
                              void* d_out, int out_size, void* d_ws, size_t ws_size,
                              hipStream_t stream) {
    const float* x   = (const float*)d_in[0];
    const int*   ei  = (const int*)d_in[1];
    const int* batch = (const int*)d_in[2];
    const float* w0a = (const float*)d_in[3];
    const float* b0a = (const float*)d_in[4];
    const float* g0  = (const float*)d_in[5];
    const float* be0 = (const float*)d_in[6];
    const float* m0  = (const float*)d_in[7];
    const float* v0  = (const float*)d_in[8];
    const float* w0b = (const float*)d_in[9];
    const float* b0b = (const float*)d_in[10];
    const float* w1a = (const float*)d_in[11];
    const float* b1a = (const float*)d_in[12];
    const float* g1  = (const float*)d_in[13];
    const float* be1 = (const float*)d_in[14];
    const float* m1  = (const float*)d_in[15];
    const float* v1  = (const float*)d_in[16];
    const float* w1b = (const float*)d_in[17];
    const float* b1b = (const float*)d_in[18];
    const float* wc  = (const float*)d_in[19];
    const float* bc  = (const float*)d_in[20];
    float* out = (float*)d_out;

    const int* srcI = ei;
    const int* dstI = ei + N_EDGES;

    // workspace layout, offsets in 4-byte units
    int* ws = (int*)d_ws;
    int*      deg       = ws;                            // 100000
    float*    pooled    = (float*)(ws + 100000);         // 32768 (contig w/ deg: one memset)
    int*      rowptr    = ws + 132768;                   // 100001
    int*      rank      = ws + 232772;                   // 1000000
    int*      sortedSrc = ws + 1232772;                  // 1000000
    _Float16* xh        = (_Float16*)(ws + 2232772);     // 6400000 halves
    _Float16* h1        = (_Float16*)(ws + 5432772);     // 6400000 halves
    float*    b1p0      = (float*)(ws + 8632772);        // 64
    float*    b1p1      = (float*)(ws + 8632836);        // 64
    int*      bsum      = ws + 8632900;                  // 200
    int*      boff      = ws + 8633100;                  // 200
    int*      gstart    = ws + 8633300;                  // 513
    _Float16* wHi       = (_Float16*)(ws + 8633816);     // 16384 halves
    _Float16* wLo       = (_Float16*)(ws + 8642008);     // 16384 halves

    // zero deg+pooled (graph-capture-safe async memset), then fused prep+hist
    hipMemsetAsync((void*)deg, 0, 132768 * sizeof(int), stream);
    prep_kernel<<<6250, 256, 0, stream>>>(x, xh, batch, dstI, deg, rank,
                                          w0a, b0a, g0, be0, m0, v0, w0b,
                                          w1a, b1a, g1, be1, m1, v1, w1b,
                                          gstart, wHi, wLo, b1p0, b1p1);

    scanA_kernel<<<SCAN_NB, 256, 0, stream>>>(deg, bsum);
    scanB_kernel<<<1, 256, 0, stream>>>(bsum, boff, rowptr);
    scanC_kernel<<<SCAN_NB, 256, 0, stream>>>(deg, boff, rowptr);
    fill_kernel<<<(N_EDGES + 255) / 256, 256, 0, stream>>>(srcI, dstI, rank, rowptr, sortedSrc);

    // conv0: h1 = relu(mlp0(x + gather(x)))   [fp16 features]
    conv_mfma<0><<<NTILES, 256, 0, stream>>>(xh, rowptr, sortedSrc,
                                             wHi, wLo, wHi + 4096, wLo + 4096,
                                             b1p0, b0b, h1, nullptr, nullptr);

    // conv1: pooled += mlp1(h1 + gather(h1))
    conv_mfma<1><<<NTILES, 256, 0, stream>>>(h1, rowptr, sortedSrc,
                                             wHi + 8192, wLo + 8192, wHi + 12288, wLo + 12288,
                                             b1p1, b1b, nullptr, batch, pooled);

    classifier_kernel<<<N_GRAPHS, 64, 0, stream>>>(pooled, gstart, wc, bc, out);
}